// Round 6
// baseline (18751.187 us; speedup 1.0000x reference)
//
#include <hip/hip_runtime.h>
#include <math.h>

// TopDownNet fp32 (threshold 2.2e-5 forbids bf16). N=131072, K=10, H=256.
// R6 = R5 with init fix (A-buffer init covered only rows 0..63; now all 256).
// Single-wave blocks, 16 samples/wave, lane ll owns cols {ll+32j} via
// column-shuffled weights. A buffer 256x16 fp32 in LDS with XOR-swizzled
// 16B blocks (stride 16, no pad): physical_blk = logical_blk ^ (((row>>2)&1)<<1),
// giving ds_read_b128 broadcast reads with compile-time offsets and ~8-way
// (cheap, rare) writes. O2 consumes h1 (registers) via a 2 KB LDS chunk
// buffer (replaces R4's 2048 ds_bpermute). Bias folded into acc init.
// LDS/block 18,432 B -> 8 blocks/CU = 2 waves/SIMD.

constexpr int NH  = 256;
constexpr int NIN = 14;
constexpr int KS  = 10;
constexpr int SPW = 16;            // samples per wave
constexpr int A4  = NH * 4;        // A buffer, float4 units (1024 = 16 KB)
constexpr int C4  = 32 * 4;        // chunk buffer, float4 units (2 KB; overlays tower)

// Column-shuffled weights/biases (rewritten every launch; capture-safe).
__device__ float g_M1[270 * 256], g_O1[270 * 256];
__device__ float g_M2[256 * 256], g_M3[256 * 256], g_O2[256 * 256];
__device__ float g_M1b[256], g_M2b[256], g_M3b[256];
__device__ float g_O1b[256], g_O2b[256], g_O3[256];

// g_W[i][8*ll + j] = W[i][ll + 32*j]
__global__ void shuffle_kernel(const float* __restrict__ M1w, const float* __restrict__ M2w,
                               const float* __restrict__ M3w, const float* __restrict__ O1w,
                               const float* __restrict__ O2w, const float* __restrict__ O3w,
                               const float* __restrict__ M1b, const float* __restrict__ M2b,
                               const float* __restrict__ M3b, const float* __restrict__ O1b,
                               const float* __restrict__ O2b) {
  const int c = threadIdx.x;          // dst col 0..255
  const int i = blockIdx.x;           // row 0..269
  const int s = (c >> 3) + 32 * (c & 7);
  g_M1[i * 256 + c] = M1w[i * 256 + s];
  g_O1[i * 256 + c] = O1w[i * 256 + s];
  if (i < 256) {
    g_M2[i * 256 + c] = M2w[i * 256 + s];
    g_M3[i * 256 + c] = M3w[i * 256 + s];
    g_O2[i * 256 + c] = O2w[i * 256 + s];
  }
  if (i == 0) {
    g_M1b[c] = M1b[s]; g_M2b[c] = M2b[s]; g_M3b[c] = M3b[s];
    g_O1b[c] = O1b[s]; g_O2b[c] = O2b[s]; g_O3[c]  = O3w[s];
  }
}

__device__ __forceinline__ void initb(float acc[8][8], const float* __restrict__ Bv,
                                      int ll) {
  float4 b0 = reinterpret_cast<const float4*>(Bv)[2 * ll];
  float4 b1 = reinterpret_cast<const float4*>(Bv)[2 * ll + 1];
  const float bb[8] = {b0.x, b0.y, b0.z, b0.w, b1.x, b1.y, b1.z, b1.w};
#pragma unroll
  for (int s = 0; s < 8; ++s)
#pragma unroll
    for (int j = 0; j < 8; ++j) acc[s][j] = bb[j];
}

// Single-chain GEMM over ROWS (multiple of 8) rows of swizzled LDS buffer.
// Xown = X4 + 2g, Xoth = X4 + (2-2g). Swizzle period 8: rows ii=0..3 read own
// blocks, ii=4..7 read the other group's physical slots (XOR by 2).
template <int ROWS>
__device__ __forceinline__ void gemmS(float acc[8][8],
                                      const float4* __restrict__ Xown,
                                      const float4* __restrict__ Xoth,
                                      const float4* __restrict__ Wp) {
#pragma unroll 1
  for (int i0 = 0; i0 < ROWS; i0 += 8) {
    const float4* Po = Xown + 4 * i0;
    const float4* Px = Xoth + 4 * i0;
    const float4* Wc = Wp + 64 * i0;
#pragma unroll
    for (int ii = 0; ii < 8; ++ii) {
      const float4* P = (ii & 4) ? Px : Po;   // compile-time select
      float4 xa = P[4 * ii];
      float4 xb = P[4 * ii + 1];
      float4 w0 = Wc[64 * ii];
      float4 w1 = Wc[64 * ii + 1];
      const float xs[8] = {xa.x, xa.y, xa.z, xa.w, xb.x, xb.y, xb.z, xb.w};
      const float wj[8] = {w0.x, w0.y, w0.z, w0.w, w1.x, w1.y, w1.z, w1.w};
#pragma unroll
      for (int s = 0; s < 8; ++s)
#pragma unroll
        for (int j = 0; j < 8; ++j)
          acc[s][j] = fmaf(xs[s], wj[j], acc[s][j]);
    }
  }
}

// Dual-chain version (fused O1+M1) over the swizzled A buffer.
template <int ROWS>
__device__ __forceinline__ void gemmS2(float accO[8][8], float accM[8][8],
                                       const float4* __restrict__ Xown,
                                       const float4* __restrict__ Xoth,
                                       const float4* __restrict__ WO,
                                       const float4* __restrict__ WM) {
#pragma unroll 1
  for (int i0 = 0; i0 < ROWS; i0 += 8) {
    const float4* Po = Xown + 4 * i0;
    const float4* Px = Xoth + 4 * i0;
    const float4* Oc = WO + 64 * i0;
    const float4* Mc = WM + 64 * i0;
#pragma unroll
    for (int ii = 0; ii < 8; ++ii) {
      const float4* P = (ii & 4) ? Px : Po;
      float4 xa = P[4 * ii];
      float4 xb = P[4 * ii + 1];
      float4 o0 = Oc[64 * ii], o1 = Oc[64 * ii + 1];
      float4 m0 = Mc[64 * ii], m1 = Mc[64 * ii + 1];
      const float xs[8] = {xa.x, xa.y, xa.z, xa.w, xb.x, xb.y, xb.z, xb.w};
      const float wo[8] = {o0.x, o0.y, o0.z, o0.w, o1.x, o1.y, o1.z, o1.w};
      const float wm[8] = {m0.x, m0.y, m0.z, m0.w, m1.x, m1.y, m1.z, m1.w};
#pragma unroll
      for (int s = 0; s < 8; ++s)
#pragma unroll
        for (int j = 0; j < 8; ++j) {
          accO[s][j] = fmaf(xs[s], wo[j], accO[s][j]);
          accM[s][j] = fmaf(xs[s], wm[j], accM[s][j]);
        }
    }
  }
}

// Tower part (14 rows, unswizzled flat stride-16 layout), dual-chain.
__device__ __forceinline__ void gemmT2(float accO[8][8], float accM[8][8],
                                       const float4* __restrict__ T4, int g,
                                       const float4* __restrict__ WO,
                                       const float4* __restrict__ WM) {
  const float4* P = T4 + 2 * g;
#pragma unroll
  for (int i = 0; i < NIN; ++i) {
    float4 xa = P[4 * i];
    float4 xb = P[4 * i + 1];
    float4 o0 = WO[64 * i], o1 = WO[64 * i + 1];
    float4 m0 = WM[64 * i], m1 = WM[64 * i + 1];
    const float xs[8] = {xa.x, xa.y, xa.z, xa.w, xb.x, xb.y, xb.z, xb.w};
    const float wo[8] = {o0.x, o0.y, o0.z, o0.w, o1.x, o1.y, o1.z, o1.w};
    const float wm[8] = {m0.x, m0.y, m0.z, m0.w, m1.x, m1.y, m1.z, m1.w};
#pragma unroll
    for (int s = 0; s < 8; ++s)
#pragma unroll
      for (int j = 0; j < 8; ++j) {
        accO[s][j] = fmaf(xs[s], wo[j], accO[s][j]);
        accM[s][j] = fmaf(xs[s], wm[j], accM[s][j]);
      }
  }
}

// relu (bias already in init) + swizzled b128 writes to rows ll+32j.
__device__ __forceinline__ void wrelu(float4* __restrict__ Y4, const float acc[8][8],
                                      int ll, int wb0) {
#pragma unroll
  for (int j = 0; j < 8; ++j) {
    const int r = ll + 32 * j;
    float4 lo, hi;
    lo.x = fmaxf(acc[0][j], 0.f);
    lo.y = fmaxf(acc[1][j], 0.f);
    lo.z = fmaxf(acc[2][j], 0.f);
    lo.w = fmaxf(acc[3][j], 0.f);
    hi.x = fmaxf(acc[4][j], 0.f);
    hi.y = fmaxf(acc[5][j], 0.f);
    hi.z = fmaxf(acc[6][j], 0.f);
    hi.w = fmaxf(acc[7][j], 0.f);
    Y4[4 * r + wb0]     = lo;   // s3w even => logical 2g,2g+1 stay adjacent
    Y4[4 * r + wb0 + 1] = hi;
  }
}

__global__ __launch_bounds__(64, 2) void topdown_kernel(
    const float* __restrict__ towers, const float* __restrict__ aggregate,
    const float* __restrict__ O3b_p, float* __restrict__ out) {
  __shared__ float4 sm4[A4 + C4];   // 18,432 B
  float4* Ab4 = sm4;
  float4* Ch4 = sm4 + A4;           // chunk scratch; overlays tower buffer
  float* Tf = reinterpret_cast<float*>(Ch4);

  const int l  = threadIdx.x;
  const int ll = l & 31;
  const int g  = l >> 5;            // lanes 0-31: samples 0-7; 32-63: 8-15
  const int n0 = blockIdx.x * SPW;

  // per-lane swizzle constants: s3w = ((ll>>2)&1)<<1 (even => blocks adjacent)
  const int s3w = ((ll >> 2) & 1) << 1;
  const int wb0 = (2 * g) ^ s3w;

  const float4* Aown = Ab4 + 2 * g;
  const float4* Aoth = Ab4 + (2 - 2 * g);
  const float4* Cown = Ch4 + 2 * g;
  const float4* Coth = Ch4 + (2 - 2 * g);

  // weight base pointers (float4, already offset by lane's 2*ll)
  const float4* O1a = reinterpret_cast<const float4*>(g_O1) + 2 * ll;
  const float4* M1a = reinterpret_cast<const float4*>(g_M1) + 2 * ll;
  const float4* O1t = O1a + 64 * NH;
  const float4* M1t = M1a + 64 * NH;
  const float4* O2p = reinterpret_cast<const float4*>(g_O2) + 2 * ll;
  const float4* M2p = reinterpret_cast<const float4*>(g_M2) + 2 * ll;
  const float4* M3p = reinterpret_cast<const float4*>(g_M3) + 2 * ll;

  // init A: ALL 1024 float4 slots (16 iters of 64 lanes); splat per row.
  // R5 BUG was m<4 (only rows 0..63 initialized). Physical slot p holds the
  // splat of its row p>>2 -- block permutation within a row is value-neutral.
#pragma unroll
  for (int m = 0; m < 16; ++m) {
    float v = aggregate[(m * 64 + l) >> 2];
    Ab4[m * 64 + l] = make_float4(v, v, v, v);
  }

  float prod[8];
#pragma unroll
  for (int s = 0; s < 8; ++s) prod[s] = 1.f;

  float accO[8][8], accM[8][8];
  const float o3bias = O3b_p[0];

  for (int kk = 0; kk < KS; ++kk) {
    const int tbase = (KS - 1 - kk) * NIN;  // reference flips along K

    // stage tower: flat layout T[i][s] at float index i*16+s; lane l's flat
    // index IS l (+64,+128,+192) -> linear conflict-free writes
    {
      const int e0 = l, e1 = l + 64, e2 = l + 128, e3 = l + 192;
      float tv0 = towers[(n0 + (e0 & 15)) * (KS * NIN) + tbase + (e0 >> 4)];
      float tv1 = towers[(n0 + (e1 & 15)) * (KS * NIN) + tbase + (e1 >> 4)];
      float tv2 = towers[(n0 + (e2 & 15)) * (KS * NIN) + tbase + (e2 >> 4)];
      float tv3 = (e3 < NIN * SPW)
                      ? towers[(n0 + (e3 & 15)) * (KS * NIN) + tbase + (e3 >> 4)]
                      : 0.f;
      Tf[e0] = tv0;
      Tf[e1] = tv1;
      Tf[e2] = tv2;
      if (e3 < NIN * SPW) Tf[e3] = tv3;
    }

    // ---- fused O1 + M1 over x = [A, T]
    initb(accO, g_O1b, ll);
    initb(accM, g_M1b, ll);
    gemmS2<NH>(accO, accM, Aown, Aoth, O1a, M1a);
    gemmT2(accO, accM, Ch4, g, O1t, M1t);

    // h1 = relu(accO) in registers
#pragma unroll
    for (int s = 0; s < 8; ++s)
#pragma unroll
      for (int j = 0; j < 8; ++j) accO[s][j] = fmaxf(accO[s][j], 0.f);

    // A <- relu(M1) in place (all A reads done; per-wave LDS is in-order)
    wrelu(Ab4, accM, ll, wb0);

    // ---- O2 via chunked h1 through LDS (32 rows/chunk, overlays tower)
    initb(accM, g_O2b, ll);  // reuse accM as acc2
#pragma unroll 1
    for (int jj = 0; jj < 8; ++jj) {
      // lane ll publishes h1[32*jj + ll], its group's 8 samples
      float4 lo = make_float4(accO[0][jj], accO[1][jj], accO[2][jj], accO[3][jj]);
      float4 hi = make_float4(accO[4][jj], accO[5][jj], accO[6][jj], accO[7][jj]);
      Ch4[4 * ll + wb0]     = lo;
      Ch4[4 * ll + wb0 + 1] = hi;
      gemmS<32>(accM, Cown, Coth, O2p + 64 * 32 * jj);
    }

    // ---- fold O3 + sigmoid + prod
    {
      float4 o0 = reinterpret_cast<const float4*>(g_O3)[2 * ll];
      float4 o1 = reinterpret_cast<const float4*>(g_O3)[2 * ll + 1];
      const float oo[8] = {o0.x, o0.y, o0.z, o0.w, o1.x, o1.y, o1.z, o1.w};
#pragma unroll
      for (int s = 0; s < 8; ++s) {
        float t = 0.f;
#pragma unroll
        for (int j = 0; j < 8; ++j)
          t = fmaf(fmaxf(accM[s][j], 0.f), oo[j], t);
        t += __shfl_xor(t, 1);
        t += __shfl_xor(t, 2);
        t += __shfl_xor(t, 4);
        t += __shfl_xor(t, 8);
        t += __shfl_xor(t, 16);  // sum within 32-group
        prod[s] *= 1.f / (1.f + expf(-(t + o3bias)));
      }
    }

    // ---- M2: A -> A (in place)
    initb(accM, g_M2b, ll);
    gemmS<NH>(accM, Aown, Aoth, M2p);
    wrelu(Ab4, accM, ll, wb0);

    // ---- M3: A -> A (in place)
    initb(accM, g_M3b, ll);
    gemmS<NH>(accM, Aown, Aoth, M3p);
    wrelu(Ab4, accM, ll, wb0);
  }

#pragma unroll
  for (int s = 0; s < 8; ++s)
    if (ll == s) out[n0 + 8 * g + s] = prod[s];
}

extern "C" void kernel_launch(void* const* d_in, const int* in_sizes, int n_in,
                              void* d_out, int out_size, void* d_ws, size_t ws_size,
                              hipStream_t stream) {
  const float* towers    = (const float*)d_in[0];
  const float* aggregate = (const float*)d_in[1];
  const float* M1w = (const float*)d_in[2];
  const float* M1b = (const float*)d_in[3];
  const float* M2w = (const float*)d_in[4];
  const float* M2b = (const float*)d_in[5];
  const float* M3w = (const float*)d_in[6];
  const float* M3b = (const float*)d_in[7];
  const float* O1w = (const float*)d_in[8];
  const float* O1b = (const float*)d_in[9];
  const float* O2w = (const float*)d_in[10];
  const float* O2b = (const float*)d_in[11];
  const float* O3w = (const float*)d_in[12];
  const float* O3b = (const float*)d_in[13];
  float* out = (float*)d_out;

  shuffle_kernel<<<270, 256, 0, stream>>>(M1w, M2w, M3w, O1w, O2w, O3w,
                                          M1b, M2b, M3b, O1b, O2b);

  const int nblocks = out_size / SPW;  // 8192
  topdown_kernel<<<nblocks, 64, 0, stream>>>(towers, aggregate, O3b, out);
}

// Round 7
// 11457.977 us; speedup vs baseline: 1.6365x; 1.6365x over previous
//
#include <hip/hip_runtime.h>
#include <math.h>

// TopDownNet fp32 (threshold 2.2e-5 forbids bf16). N=131072, K=10, H=256.
// R7 = R6 with spill-safe unrolling. R6's fully-unrolled 8-row gemm bodies
// let LLVM hoist ~192 temp regs above the FMA block -> scratch spill
// (WRITE_SIZE 30 GB, VALU 33%). R4 proved unroll-2 dual-chain fits in regs.
// Here: each 8-row swizzle period = two 4-row sub-loops (rows 0-3 own blocks,
// 4-7 other blocks; select stays compile-time), #pragma unroll 2.
// Layout: single-wave blocks, 16 samples/wave, lane ll owns cols {ll+32j}
// via column-shuffled weights; A buffer 256x16 fp32, XOR-swizzled 16B blocks
// (physical_blk = logical_blk ^ (((row>>2)&1)<<1)) -> ds_read_b128 broadcast
// reads; O2 via 2 KB LDS chunk buffer; bias folded into acc init.
// LDS 18,432 B -> 8 blocks/CU = 2 waves/SIMD.

constexpr int NH  = 256;
constexpr int NIN = 14;
constexpr int KS  = 10;
constexpr int SPW = 16;            // samples per wave
constexpr int A4  = NH * 4;        // A buffer, float4 units (1024 = 16 KB)
constexpr int C4  = 32 * 4;        // chunk buffer, float4 units (2 KB; overlays tower)

// Column-shuffled weights/biases (rewritten every launch; capture-safe).
__device__ float g_M1[270 * 256], g_O1[270 * 256];
__device__ float g_M2[256 * 256], g_M3[256 * 256], g_O2[256 * 256];
__device__ float g_M1b[256], g_M2b[256], g_M3b[256];
__device__ float g_O1b[256], g_O2b[256], g_O3[256];

// g_W[i][8*ll + j] = W[i][ll + 32*j]
__global__ void shuffle_kernel(const float* __restrict__ M1w, const float* __restrict__ M2w,
                               const float* __restrict__ M3w, const float* __restrict__ O1w,
                               const float* __restrict__ O2w, const float* __restrict__ O3w,
                               const float* __restrict__ M1b, const float* __restrict__ M2b,
                               const float* __restrict__ M3b, const float* __restrict__ O1b,
                               const float* __restrict__ O2b) {
  const int c = threadIdx.x;          // dst col 0..255
  const int i = blockIdx.x;           // row 0..269
  const int s = (c >> 3) + 32 * (c & 7);
  g_M1[i * 256 + c] = M1w[i * 256 + s];
  g_O1[i * 256 + c] = O1w[i * 256 + s];
  if (i < 256) {
    g_M2[i * 256 + c] = M2w[i * 256 + s];
    g_M3[i * 256 + c] = M3w[i * 256 + s];
    g_O2[i * 256 + c] = O2w[i * 256 + s];
  }
  if (i == 0) {
    g_M1b[c] = M1b[s]; g_M2b[c] = M2b[s]; g_M3b[c] = M3b[s];
    g_O1b[c] = O1b[s]; g_O2b[c] = O2b[s]; g_O3[c]  = O3w[s];
  }
}

__device__ __forceinline__ void initb(float acc[8][8], const float* __restrict__ Bv,
                                      int ll) {
  float4 b0 = reinterpret_cast<const float4*>(Bv)[2 * ll];
  float4 b1 = reinterpret_cast<const float4*>(Bv)[2 * ll + 1];
  const float bb[8] = {b0.x, b0.y, b0.z, b0.w, b1.x, b1.y, b1.z, b1.w};
#pragma unroll
  for (int s = 0; s < 8; ++s)
#pragma unroll
    for (int j = 0; j < 8; ++j) acc[s][j] = bb[j];
}

__device__ __forceinline__ void fma_row(float acc[8][8], float4 xa, float4 xb,
                                        float4 w0, float4 w1) {
  const float xs[8] = {xa.x, xa.y, xa.z, xa.w, xb.x, xb.y, xb.z, xb.w};
  const float wj[8] = {w0.x, w0.y, w0.z, w0.w, w1.x, w1.y, w1.z, w1.w};
#pragma unroll
  for (int s = 0; s < 8; ++s)
#pragma unroll
    for (int j = 0; j < 8; ++j)
      acc[s][j] = fmaf(xs[s], wj[j], acc[s][j]);
}

// Single-chain GEMM over ROWS (multiple of 8) rows of swizzled LDS buffer.
// Rows ii%8 in 0..3 read own blocks; 4..7 read the other group's slots.
template <int ROWS>
__device__ __forceinline__ void gemmS(float acc[8][8],
                                      const float4* __restrict__ Xown,
                                      const float4* __restrict__ Xoth,
                                      const float4* __restrict__ Wp) {
#pragma unroll 1
  for (int i0 = 0; i0 < ROWS; i0 += 8) {
    const float4* Po = Xown + 4 * i0;
    const float4* Px = Xoth + 4 * i0;
    const float4* Wc = Wp + 64 * i0;
#pragma unroll 2
    for (int ii = 0; ii < 4; ++ii)
      fma_row(acc, Po[4 * ii], Po[4 * ii + 1], Wc[64 * ii], Wc[64 * ii + 1]);
#pragma unroll 2
    for (int ii = 4; ii < 8; ++ii)
      fma_row(acc, Px[4 * ii], Px[4 * ii + 1], Wc[64 * ii], Wc[64 * ii + 1]);
  }
}

// Dual-chain version (fused O1+M1) over the swizzled A buffer.
template <int ROWS>
__device__ __forceinline__ void gemmS2(float accO[8][8], float accM[8][8],
                                       const float4* __restrict__ Xown,
                                       const float4* __restrict__ Xoth,
                                       const float4* __restrict__ WO,
                                       const float4* __restrict__ WM) {
#pragma unroll 1
  for (int i0 = 0; i0 < ROWS; i0 += 8) {
    const float4* Po = Xown + 4 * i0;
    const float4* Px = Xoth + 4 * i0;
    const float4* Oc = WO + 64 * i0;
    const float4* Mc = WM + 64 * i0;
#pragma unroll 2
    for (int ii = 0; ii < 4; ++ii) {
      float4 xa = Po[4 * ii], xb = Po[4 * ii + 1];
      fma_row(accO, xa, xb, Oc[64 * ii], Oc[64 * ii + 1]);
      fma_row(accM, xa, xb, Mc[64 * ii], Mc[64 * ii + 1]);
    }
#pragma unroll 2
    for (int ii = 4; ii < 8; ++ii) {
      float4 xa = Px[4 * ii], xb = Px[4 * ii + 1];
      fma_row(accO, xa, xb, Oc[64 * ii], Oc[64 * ii + 1]);
      fma_row(accM, xa, xb, Mc[64 * ii], Mc[64 * ii + 1]);
    }
  }
}

// Tower part (14 rows, unswizzled flat stride-16 layout), dual-chain.
__device__ __forceinline__ void gemmT2(float accO[8][8], float accM[8][8],
                                       const float4* __restrict__ T4, int g,
                                       const float4* __restrict__ WO,
                                       const float4* __restrict__ WM) {
  const float4* P = T4 + 2 * g;
#pragma unroll 2
  for (int i = 0; i < NIN; ++i) {
    float4 xa = P[4 * i], xb = P[4 * i + 1];
    fma_row(accO, xa, xb, WO[64 * i], WO[64 * i + 1]);
    fma_row(accM, xa, xb, WM[64 * i], WM[64 * i + 1]);
  }
}

// relu (bias already in init) + swizzled b128 writes to rows ll+32j.
__device__ __forceinline__ void wrelu(float4* __restrict__ Y4, const float acc[8][8],
                                      int ll, int wb0) {
#pragma unroll
  for (int j = 0; j < 8; ++j) {
    const int r = ll + 32 * j;
    float4 lo, hi;
    lo.x = fmaxf(acc[0][j], 0.f);
    lo.y = fmaxf(acc[1][j], 0.f);
    lo.z = fmaxf(acc[2][j], 0.f);
    lo.w = fmaxf(acc[3][j], 0.f);
    hi.x = fmaxf(acc[4][j], 0.f);
    hi.y = fmaxf(acc[5][j], 0.f);
    hi.z = fmaxf(acc[6][j], 0.f);
    hi.w = fmaxf(acc[7][j], 0.f);
    Y4[4 * r + wb0]     = lo;   // s3w even => logical 2g,2g+1 stay adjacent
    Y4[4 * r + wb0 + 1] = hi;
  }
}

__global__ __launch_bounds__(64, 2) void topdown_kernel(
    const float* __restrict__ towers, const float* __restrict__ aggregate,
    const float* __restrict__ O3b_p, float* __restrict__ out) {
  __shared__ float4 sm4[A4 + C4];   // 18,432 B
  float4* Ab4 = sm4;
  float4* Ch4 = sm4 + A4;           // chunk scratch; overlays tower buffer
  float* Tf = reinterpret_cast<float*>(Ch4);

  const int l  = threadIdx.x;
  const int ll = l & 31;
  const int g  = l >> 5;            // lanes 0-31: samples 0-7; 32-63: 8-15
  const int n0 = blockIdx.x * SPW;

  // per-lane swizzle constants: s3w = ((ll>>2)&1)<<1 (even => blocks adjacent)
  const int s3w = ((ll >> 2) & 1) << 1;
  const int wb0 = (2 * g) ^ s3w;

  const float4* Aown = Ab4 + 2 * g;
  const float4* Aoth = Ab4 + (2 - 2 * g);
  const float4* Cown = Ch4 + 2 * g;
  const float4* Coth = Ch4 + (2 - 2 * g);

  // weight base pointers (float4, already offset by lane's 2*ll)
  const float4* O1a = reinterpret_cast<const float4*>(g_O1) + 2 * ll;
  const float4* M1a = reinterpret_cast<const float4*>(g_M1) + 2 * ll;
  const float4* O1t = O1a + 64 * NH;
  const float4* M1t = M1a + 64 * NH;
  const float4* O2p = reinterpret_cast<const float4*>(g_O2) + 2 * ll;
  const float4* M2p = reinterpret_cast<const float4*>(g_M2) + 2 * ll;
  const float4* M3p = reinterpret_cast<const float4*>(g_M3) + 2 * ll;

  // init A: ALL 1024 float4 slots; physical slot p holds splat of row p>>2
  // (block permutation within a row is value-neutral for a splat).
#pragma unroll
  for (int m = 0; m < 16; ++m) {
    float v = aggregate[(m * 64 + l) >> 2];
    Ab4[m * 64 + l] = make_float4(v, v, v, v);
  }

  float prod[8];
#pragma unroll
  for (int s = 0; s < 8; ++s) prod[s] = 1.f;

  float accO[8][8], accM[8][8];
  const float o3bias = O3b_p[0];

  for (int kk = 0; kk < KS; ++kk) {
    const int tbase = (KS - 1 - kk) * NIN;  // reference flips along K

    // stage tower: flat layout T[i][s] at float index i*16+s; lane l's flat
    // index IS l (+64,+128,+192) -> linear conflict-free writes
    {
      const int e0 = l, e1 = l + 64, e2 = l + 128, e3 = l + 192;
      float tv0 = towers[(n0 + (e0 & 15)) * (KS * NIN) + tbase + (e0 >> 4)];
      float tv1 = towers[(n0 + (e1 & 15)) * (KS * NIN) + tbase + (e1 >> 4)];
      float tv2 = towers[(n0 + (e2 & 15)) * (KS * NIN) + tbase + (e2 >> 4)];
      float tv3 = (e3 < NIN * SPW)
                      ? towers[(n0 + (e3 & 15)) * (KS * NIN) + tbase + (e3 >> 4)]
                      : 0.f;
      Tf[e0] = tv0;
      Tf[e1] = tv1;
      Tf[e2] = tv2;
      if (e3 < NIN * SPW) Tf[e3] = tv3;
    }

    // ---- fused O1 + M1 over x = [A, T]
    initb(accO, g_O1b, ll);
    initb(accM, g_M1b, ll);
    gemmS2<NH>(accO, accM, Aown, Aoth, O1a, M1a);
    gemmT2(accO, accM, Ch4, g, O1t, M1t);

    // h1 = relu(accO) in registers
#pragma unroll
    for (int s = 0; s < 8; ++s)
#pragma unroll
      for (int j = 0; j < 8; ++j) accO[s][j] = fmaxf(accO[s][j], 0.f);

    // A <- relu(M1) in place (all A reads done; per-wave LDS is in-order)
    wrelu(Ab4, accM, ll, wb0);

    // ---- O2 via chunked h1 through LDS (32 rows/chunk, overlays tower)
    initb(accM, g_O2b, ll);  // reuse accM as acc2
#pragma unroll 1
    for (int jj = 0; jj < 8; ++jj) {
      // lane ll publishes h1[32*jj + ll], its group's 8 samples
      float4 lo = make_float4(accO[0][jj], accO[1][jj], accO[2][jj], accO[3][jj]);
      float4 hi = make_float4(accO[4][jj], accO[5][jj], accO[6][jj], accO[7][jj]);
      Ch4[4 * ll + wb0]     = lo;
      Ch4[4 * ll + wb0 + 1] = hi;
      gemmS<32>(accM, Cown, Coth, O2p + 64 * 32 * jj);
    }

    // ---- fold O3 + sigmoid + prod
    {
      float4 o0 = reinterpret_cast<const float4*>(g_O3)[2 * ll];
      float4 o1 = reinterpret_cast<const float4*>(g_O3)[2 * ll + 1];
      const float oo[8] = {o0.x, o0.y, o0.z, o0.w, o1.x, o1.y, o1.z, o1.w};
#pragma unroll
      for (int s = 0; s < 8; ++s) {
        float t = 0.f;
#pragma unroll
        for (int j = 0; j < 8; ++j)
          t = fmaf(fmaxf(accM[s][j], 0.f), oo[j], t);
        t += __shfl_xor(t, 1);
        t += __shfl_xor(t, 2);
        t += __shfl_xor(t, 4);
        t += __shfl_xor(t, 8);
        t += __shfl_xor(t, 16);  // sum within 32-group
        prod[s] *= 1.f / (1.f + expf(-(t + o3bias)));
      }
    }

    // ---- M2: A -> A (in place)
    initb(accM, g_M2b, ll);
    gemmS<NH>(accM, Aown, Aoth, M2p);
    wrelu(Ab4, accM, ll, wb0);

    // ---- M3: A -> A (in place)
    initb(accM, g_M3b, ll);
    gemmS<NH>(accM, Aown, Aoth, M3p);
    wrelu(Ab4, accM, ll, wb0);
  }

#pragma unroll
  for (int s = 0; s < 8; ++s)
    if (ll == s) out[n0 + 8 * g + s] = prod[s];
}

extern "C" void kernel_launch(void* const* d_in, const int* in_sizes, int n_in,
                              void* d_out, int out_size, void* d_ws, size_t ws_size,
                              hipStream_t stream) {
  const float* towers    = (const float*)d_in[0];
  const float* aggregate = (const float*)d_in[1];
  const float* M1w = (const float*)d_in[2];
  const float* M1b = (const float*)d_in[3];
  const float* M2w = (const float*)d_in[4];
  const float* M2b = (const float*)d_in[5];
  const float* M3w = (const float*)d_in[6];
  const float* M3b = (const float*)d_in[7];
  const float* O1w = (const float*)d_in[8];
  const float* O1b = (const float*)d_in[9];
  const float* O2w = (const float*)d_in[10];
  const float* O2b = (const float*)d_in[11];
  const float* O3w = (const float*)d_in[12];
  const float* O3b = (const float*)d_in[13];
  float* out = (float*)d_out;

  shuffle_kernel<<<270, 256, 0, stream>>>(M1w, M2w, M3w, O1w, O2w, O3w,
                                          M1b, M2b, M3b, O1b, O2b);

  const int nblocks = out_size / SPW;  // 8192
  topdown_kernel<<<nblocks, 64, 0, stream>>>(towers, aggregate, O3b, out);
}

// Round 8
// 11171.763 us; speedup vs baseline: 1.6784x; 1.0256x over previous
//
#include <hip/hip_runtime.h>
#include <math.h>

// TopDownNet fp32 (threshold 2.2e-5 forbids bf16). N=131072, K=10, H=256.
// R8 = R7 + full unroll of the O2 chunk loop. R7's `#pragma unroll 1 for jj`
// read accO[s][jj] with a RUNTIME index -> LLVM demoted accO[8][8] to scratch
// (array demotion, not reg pressure: VGPR=124), so all 270x64 O1-phase FMA
// accumulations became scratch load-modify-stores (WRITE_SIZE 2.9 GB, VALU 66%).
// Constant jj restores SROA -> accO in registers.
// Layout: single-wave blocks, 16 samples/wave, lane ll owns cols {ll+32j}
// via column-shuffled weights; A buffer 256x16 fp32, XOR-swizzled 16B blocks
// (physical_blk = logical_blk ^ (((row>>2)&1)<<1)) -> ds_read_b128 broadcast
// reads; O2 via 2 KB LDS chunk buffer; bias folded into acc init.
// LDS 18,432 B -> 8 blocks/CU = 2 waves/SIMD.

constexpr int NH  = 256;
constexpr int NIN = 14;
constexpr int KS  = 10;
constexpr int SPW = 16;            // samples per wave
constexpr int A4  = NH * 4;        // A buffer, float4 units (1024 = 16 KB)
constexpr int C4  = 32 * 4;        // chunk buffer, float4 units (2 KB; overlays tower)

// Column-shuffled weights/biases (rewritten every launch; capture-safe).
__device__ float g_M1[270 * 256], g_O1[270 * 256];
__device__ float g_M2[256 * 256], g_M3[256 * 256], g_O2[256 * 256];
__device__ float g_M1b[256], g_M2b[256], g_M3b[256];
__device__ float g_O1b[256], g_O2b[256], g_O3[256];

// g_W[i][8*ll + j] = W[i][ll + 32*j]
__global__ void shuffle_kernel(const float* __restrict__ M1w, const float* __restrict__ M2w,
                               const float* __restrict__ M3w, const float* __restrict__ O1w,
                               const float* __restrict__ O2w, const float* __restrict__ O3w,
                               const float* __restrict__ M1b, const float* __restrict__ M2b,
                               const float* __restrict__ M3b, const float* __restrict__ O1b,
                               const float* __restrict__ O2b) {
  const int c = threadIdx.x;          // dst col 0..255
  const int i = blockIdx.x;           // row 0..269
  const int s = (c >> 3) + 32 * (c & 7);
  g_M1[i * 256 + c] = M1w[i * 256 + s];
  g_O1[i * 256 + c] = O1w[i * 256 + s];
  if (i < 256) {
    g_M2[i * 256 + c] = M2w[i * 256 + s];
    g_M3[i * 256 + c] = M3w[i * 256 + s];
    g_O2[i * 256 + c] = O2w[i * 256 + s];
  }
  if (i == 0) {
    g_M1b[c] = M1b[s]; g_M2b[c] = M2b[s]; g_M3b[c] = M3b[s];
    g_O1b[c] = O1b[s]; g_O2b[c] = O2b[s]; g_O3[c]  = O3w[s];
  }
}

__device__ __forceinline__ void initb(float acc[8][8], const float* __restrict__ Bv,
                                      int ll) {
  float4 b0 = reinterpret_cast<const float4*>(Bv)[2 * ll];
  float4 b1 = reinterpret_cast<const float4*>(Bv)[2 * ll + 1];
  const float bb[8] = {b0.x, b0.y, b0.z, b0.w, b1.x, b1.y, b1.z, b1.w};
#pragma unroll
  for (int s = 0; s < 8; ++s)
#pragma unroll
    for (int j = 0; j < 8; ++j) acc[s][j] = bb[j];
}

__device__ __forceinline__ void fma_row(float acc[8][8], float4 xa, float4 xb,
                                        float4 w0, float4 w1) {
  const float xs[8] = {xa.x, xa.y, xa.z, xa.w, xb.x, xb.y, xb.z, xb.w};
  const float wj[8] = {w0.x, w0.y, w0.z, w0.w, w1.x, w1.y, w1.z, w1.w};
#pragma unroll
  for (int s = 0; s < 8; ++s)
#pragma unroll
    for (int j = 0; j < 8; ++j)
      acc[s][j] = fmaf(xs[s], wj[j], acc[s][j]);
}

// Single-chain GEMM over ROWS (multiple of 8) rows of swizzled LDS buffer.
// Rows ii%8 in 0..3 read own blocks; 4..7 read the other group's slots.
template <int ROWS>
__device__ __forceinline__ void gemmS(float acc[8][8],
                                      const float4* __restrict__ Xown,
                                      const float4* __restrict__ Xoth,
                                      const float4* __restrict__ Wp) {
#pragma unroll 1
  for (int i0 = 0; i0 < ROWS; i0 += 8) {
    const float4* Po = Xown + 4 * i0;
    const float4* Px = Xoth + 4 * i0;
    const float4* Wc = Wp + 64 * i0;
#pragma unroll 2
    for (int ii = 0; ii < 4; ++ii)
      fma_row(acc, Po[4 * ii], Po[4 * ii + 1], Wc[64 * ii], Wc[64 * ii + 1]);
#pragma unroll 2
    for (int ii = 4; ii < 8; ++ii)
      fma_row(acc, Px[4 * ii], Px[4 * ii + 1], Wc[64 * ii], Wc[64 * ii + 1]);
  }
}

// Dual-chain version (fused O1+M1) over the swizzled A buffer.
template <int ROWS>
__device__ __forceinline__ void gemmS2(float accO[8][8], float accM[8][8],
                                       const float4* __restrict__ Xown,
                                       const float4* __restrict__ Xoth,
                                       const float4* __restrict__ WO,
                                       const float4* __restrict__ WM) {
#pragma unroll 1
  for (int i0 = 0; i0 < ROWS; i0 += 8) {
    const float4* Po = Xown + 4 * i0;
    const float4* Px = Xoth + 4 * i0;
    const float4* Oc = WO + 64 * i0;
    const float4* Mc = WM + 64 * i0;
#pragma unroll 2
    for (int ii = 0; ii < 4; ++ii) {
      float4 xa = Po[4 * ii], xb = Po[4 * ii + 1];
      fma_row(accO, xa, xb, Oc[64 * ii], Oc[64 * ii + 1]);
      fma_row(accM, xa, xb, Mc[64 * ii], Mc[64 * ii + 1]);
    }
#pragma unroll 2
    for (int ii = 4; ii < 8; ++ii) {
      float4 xa = Px[4 * ii], xb = Px[4 * ii + 1];
      fma_row(accO, xa, xb, Oc[64 * ii], Oc[64 * ii + 1]);
      fma_row(accM, xa, xb, Mc[64 * ii], Mc[64 * ii + 1]);
    }
  }
}

// Tower part (14 rows, unswizzled flat stride-16 layout), dual-chain.
__device__ __forceinline__ void gemmT2(float accO[8][8], float accM[8][8],
                                       const float4* __restrict__ T4, int g,
                                       const float4* __restrict__ WO,
                                       const float4* __restrict__ WM) {
  const float4* P = T4 + 2 * g;
#pragma unroll 2
  for (int i = 0; i < NIN; ++i) {
    float4 xa = P[4 * i], xb = P[4 * i + 1];
    fma_row(accO, xa, xb, WO[64 * i], WO[64 * i + 1]);
    fma_row(accM, xa, xb, WM[64 * i], WM[64 * i + 1]);
  }
}

// relu (bias already in init) + swizzled b128 writes to rows ll+32j.
__device__ __forceinline__ void wrelu(float4* __restrict__ Y4, const float acc[8][8],
                                      int ll, int wb0) {
#pragma unroll
  for (int j = 0; j < 8; ++j) {
    const int r = ll + 32 * j;
    float4 lo, hi;
    lo.x = fmaxf(acc[0][j], 0.f);
    lo.y = fmaxf(acc[1][j], 0.f);
    lo.z = fmaxf(acc[2][j], 0.f);
    lo.w = fmaxf(acc[3][j], 0.f);
    hi.x = fmaxf(acc[4][j], 0.f);
    hi.y = fmaxf(acc[5][j], 0.f);
    hi.z = fmaxf(acc[6][j], 0.f);
    hi.w = fmaxf(acc[7][j], 0.f);
    Y4[4 * r + wb0]     = lo;   // s3w even => logical 2g,2g+1 stay adjacent
    Y4[4 * r + wb0 + 1] = hi;
  }
}

__global__ __launch_bounds__(64, 2) void topdown_kernel(
    const float* __restrict__ towers, const float* __restrict__ aggregate,
    const float* __restrict__ O3b_p, float* __restrict__ out) {
  __shared__ float4 sm4[A4 + C4];   // 18,432 B
  float4* Ab4 = sm4;
  float4* Ch4 = sm4 + A4;           // chunk scratch; overlays tower buffer
  float* Tf = reinterpret_cast<float*>(Ch4);

  const int l  = threadIdx.x;
  const int ll = l & 31;
  const int g  = l >> 5;            // lanes 0-31: samples 0-7; 32-63: 8-15
  const int n0 = blockIdx.x * SPW;

  // per-lane swizzle constants: s3w = ((ll>>2)&1)<<1 (even => blocks adjacent)
  const int s3w = ((ll >> 2) & 1) << 1;
  const int wb0 = (2 * g) ^ s3w;

  const float4* Aown = Ab4 + 2 * g;
  const float4* Aoth = Ab4 + (2 - 2 * g);
  const float4* Cown = Ch4 + 2 * g;
  const float4* Coth = Ch4 + (2 - 2 * g);

  // weight base pointers (float4, already offset by lane's 2*ll)
  const float4* O1a = reinterpret_cast<const float4*>(g_O1) + 2 * ll;
  const float4* M1a = reinterpret_cast<const float4*>(g_M1) + 2 * ll;
  const float4* O1t = O1a + 64 * NH;
  const float4* M1t = M1a + 64 * NH;
  const float4* O2p = reinterpret_cast<const float4*>(g_O2) + 2 * ll;
  const float4* M2p = reinterpret_cast<const float4*>(g_M2) + 2 * ll;
  const float4* M3p = reinterpret_cast<const float4*>(g_M3) + 2 * ll;

  // init A: ALL 1024 float4 slots; physical slot p holds splat of row p>>2
  // (block permutation within a row is value-neutral for a splat).
#pragma unroll
  for (int m = 0; m < 16; ++m) {
    float v = aggregate[(m * 64 + l) >> 2];
    Ab4[m * 64 + l] = make_float4(v, v, v, v);
  }

  float prod[8];
#pragma unroll
  for (int s = 0; s < 8; ++s) prod[s] = 1.f;

  float accO[8][8], accM[8][8];
  const float o3bias = O3b_p[0];

  for (int kk = 0; kk < KS; ++kk) {
    const int tbase = (KS - 1 - kk) * NIN;  // reference flips along K

    // stage tower: flat layout T[i][s] at float index i*16+s; lane l's flat
    // index IS l (+64,+128,+192) -> linear conflict-free writes
    {
      const int e0 = l, e1 = l + 64, e2 = l + 128, e3 = l + 192;
      float tv0 = towers[(n0 + (e0 & 15)) * (KS * NIN) + tbase + (e0 >> 4)];
      float tv1 = towers[(n0 + (e1 & 15)) * (KS * NIN) + tbase + (e1 >> 4)];
      float tv2 = towers[(n0 + (e2 & 15)) * (KS * NIN) + tbase + (e2 >> 4)];
      float tv3 = (e3 < NIN * SPW)
                      ? towers[(n0 + (e3 & 15)) * (KS * NIN) + tbase + (e3 >> 4)]
                      : 0.f;
      Tf[e0] = tv0;
      Tf[e1] = tv1;
      Tf[e2] = tv2;
      if (e3 < NIN * SPW) Tf[e3] = tv3;
    }

    // ---- fused O1 + M1 over x = [A, T]
    initb(accO, g_O1b, ll);
    initb(accM, g_M1b, ll);
    gemmS2<NH>(accO, accM, Aown, Aoth, O1a, M1a);
    gemmT2(accO, accM, Ch4, g, O1t, M1t);

    // h1 = relu(accO) in registers
#pragma unroll
    for (int s = 0; s < 8; ++s)
#pragma unroll
      for (int j = 0; j < 8; ++j) accO[s][j] = fmaxf(accO[s][j], 0.f);

    // A <- relu(M1) in place (all A reads done; per-wave LDS is in-order)
    wrelu(Ab4, accM, ll, wb0);

    // ---- O2 via chunked h1 through LDS (32 rows/chunk, overlays tower)
    // FULLY UNROLLED so accO[s][jj] has constant indices (keeps accO in regs;
    // runtime jj in R6/R7 demoted accO to scratch -> GB-scale spill traffic).
    initb(accM, g_O2b, ll);  // reuse accM as acc2
#pragma unroll
    for (int jj = 0; jj < 8; ++jj) {
      // lane ll publishes h1[32*jj + ll], its group's 8 samples
      float4 lo = make_float4(accO[0][jj], accO[1][jj], accO[2][jj], accO[3][jj]);
      float4 hi = make_float4(accO[4][jj], accO[5][jj], accO[6][jj], accO[7][jj]);
      Ch4[4 * ll + wb0]     = lo;
      Ch4[4 * ll + wb0 + 1] = hi;
      gemmS<32>(accM, Cown, Coth, O2p + 64 * 32 * jj);
    }

    // ---- fold O3 + sigmoid + prod
    {
      float4 o0 = reinterpret_cast<const float4*>(g_O3)[2 * ll];
      float4 o1 = reinterpret_cast<const float4*>(g_O3)[2 * ll + 1];
      const float oo[8] = {o0.x, o0.y, o0.z, o0.w, o1.x, o1.y, o1.z, o1.w};
#pragma unroll
      for (int s = 0; s < 8; ++s) {
        float t = 0.f;
#pragma unroll
        for (int j = 0; j < 8; ++j)
          t = fmaf(fmaxf(accM[s][j], 0.f), oo[j], t);
        t += __shfl_xor(t, 1);
        t += __shfl_xor(t, 2);
        t += __shfl_xor(t, 4);
        t += __shfl_xor(t, 8);
        t += __shfl_xor(t, 16);  // sum within 32-group
        prod[s] *= 1.f / (1.f + expf(-(t + o3bias)));
      }
    }

    // ---- M2: A -> A (in place)
    initb(accM, g_M2b, ll);
    gemmS<NH>(accM, Aown, Aoth, M2p);
    wrelu(Ab4, accM, ll, wb0);

    // ---- M3: A -> A (in place)
    initb(accM, g_M3b, ll);
    gemmS<NH>(accM, Aown, Aoth, M3p);
    wrelu(Ab4, accM, ll, wb0);
  }

#pragma unroll
  for (int s = 0; s < 8; ++s)
    if (ll == s) out[n0 + 8 * g + s] = prod[s];
}

extern "C" void kernel_launch(void* const* d_in, const int* in_sizes, int n_in,
                              void* d_out, int out_size, void* d_ws, size_t ws_size,
                              hipStream_t stream) {
  const float* towers    = (const float*)d_in[0];
  const float* aggregate = (const float*)d_in[1];
  const float* M1w = (const float*)d_in[2];
  const float* M1b = (const float*)d_in[3];
  const float* M2w = (const float*)d_in[4];
  const float* M2b = (const float*)d_in[5];
  const float* M3w = (const float*)d_in[6];
  const float* M3b = (const float*)d_in[7];
  const float* O1w = (const float*)d_in[8];
  const float* O1b = (const float*)d_in[9];
  const float* O2w = (const float*)d_in[10];
  const float* O2b = (const float*)d_in[11];
  const float* O3w = (const float*)d_in[12];
  const float* O3b = (const float*)d_in[13];
  float* out = (float*)d_out;

  shuffle_kernel<<<270, 256, 0, stream>>>(M1w, M2w, M3w, O1w, O2w, O3w,
                                          M1b, M2b, M3b, O1b, O2b);

  const int nblocks = out_size / SPW;  // 8192
  topdown_kernel<<<nblocks, 64, 0, stream>>>(towers, aggregate, O3b, out);
}